// Round 6
// baseline (364.093 us; speedup 1.0000x reference)
//
#include <hip/hip_runtime.h>
#include <hip/hip_fp16.h>
#include <math.h>

#define N_NODES 100000
#define N_EDGES 1000000
#define IN_DIM 64
#define HID 64
#define NC 30
#define NCP 32              // padded row width for fp16/fp8 feature rows
#define REG_C 0.01f

#define NTILES (N_NODES / 16)     // 6250
#define NBUCK 391                 // 256-node tiles: ceil(100000/256)
#define EPB_A 2048                // edges per deg block
#define NBLK_A 489                // ceil(1M / 2048)
#define GEMM_BLOCKS 512

typedef _Float16 half8 __attribute__((ext_vector_type(8)));
typedef _Float16 h16x4 __attribute__((ext_vector_type(4)));
typedef float f32x4 __attribute__((ext_vector_type(4)));
typedef float f32x2 __attribute__((ext_vector_type(2)));

__device__ __forceinline__ unsigned char enc_fp8(float v) {
    return (unsigned char)(__builtin_amdgcn_cvt_pk_fp8_f32(v, v, 0, false) & 0xFF);
}
// decode 4 packed fp8 bytes -> 4 floats (byte-select must be literal constants)
__device__ __forceinline__ f32x4 dec_fp8x4(unsigned u) {
    f32x4 r;
    r[0] = __builtin_amdgcn_cvt_f32_fp8((int)u, 0);
    r[1] = __builtin_amdgcn_cvt_f32_fp8((int)u, 1);
    r[2] = __builtin_amdgcn_cvt_f32_fp8((int)u, 2);
    r[3] = __builtin_amdgcn_cvt_f32_fp8((int)u, 3);
    return r;
}
__device__ __forceinline__ float dot4_fp8(unsigned a, unsigned b) {
    float s = __builtin_amdgcn_cvt_f32_fp8((int)a, 0) * __builtin_amdgcn_cvt_f32_fp8((int)b, 0);
    s += __builtin_amdgcn_cvt_f32_fp8((int)a, 1) * __builtin_amdgcn_cvt_f32_fp8((int)b, 1);
    s += __builtin_amdgcn_cvt_f32_fp8((int)a, 2) * __builtin_amdgcn_cvt_f32_fp8((int)b, 2);
    s += __builtin_amdgcn_cvt_f32_fp8((int)a, 3) * __builtin_amdgcn_cvt_f32_fp8((int)b, 3);
    return s;
}

// ------- fused: global-atomic degree/count + h1=fp8(x@W1) (memory ∥ MFMA blocks) ---
__global__ void deg_gemm(const int* __restrict__ dst, const float* __restrict__ w,
                         int* __restrict__ cnt, float* __restrict__ degf,
                         const float* __restrict__ X, const float* __restrict__ W,
                         unsigned char* __restrict__ H8) {
    if (blockIdx.x < NBLK_A) {
        int e0 = blockIdx.x * EPB_A;
#pragma unroll
        for (int j = 0; j < 8; ++j) {
            int e = e0 + j * 256 + threadIdx.x;
            if (e < N_EDGES) {
                int d = dst[e];
                atomicAdd(&cnt[d], 1);
                atomicAdd(&degf[d], w[e]);
            }
        }
        return;
    }
    // ---- GEMM part ----
    const int lane = threadIdx.x & 63;
    const int wave = threadIdx.x >> 6;
    const int qd = lane >> 4;
    const int l = lane & 15;
    half8 bfrag[2][4];
#pragma unroll
    for (int kb = 0; kb < 2; ++kb)
#pragma unroll
        for (int t = 0; t < 4; ++t)
#pragma unroll
            for (int j = 0; j < 8; ++j)
                bfrag[kb][t][j] = (_Float16)W[(kb * 32 + qd * 8 + j) * 64 + t * 16 + l];

    const int gb = blockIdx.x - NBLK_A;
    const int waveStride = GEMM_BLOCKS * 4;
    for (int ntile = gb * 4 + wave; ntile < NTILES; ntile += waveStride) {
        const int node0 = ntile * 16;
        const float* arow = X + (size_t)(node0 + l) * 64 + qd * 8;
        half8 af0, af1;
#pragma unroll
        for (int j = 0; j < 8; ++j) {
            af0[j] = (_Float16)arow[j];
            af1[j] = (_Float16)arow[32 + j];
        }
        f32x4 acc[4];
#pragma unroll
        for (int t = 0; t < 4; ++t) acc[t] = (f32x4){0.f, 0.f, 0.f, 0.f};
#pragma unroll
        for (int t = 0; t < 4; ++t) {
            acc[t] = __builtin_amdgcn_mfma_f32_16x16x32_f16(af0, bfrag[0][t], acc[t], 0, 0, 0);
            acc[t] = __builtin_amdgcn_mfma_f32_16x16x32_f16(af1, bfrag[1][t], acc[t], 0, 0, 0);
        }
#pragma unroll
        for (int t = 0; t < 4; ++t)
#pragma unroll
            for (int rr = 0; rr < 4; ++rr)
                H8[(size_t)(node0 + qd * 4 + rr) * 64 + t * 16 + l] = enc_fp8(acc[t][rr]);
    }
}

// ------- node_scan: per-256-node tile LDS scan of cnt + dinv/invdeg ---------------
__global__ void node_scan(const int* __restrict__ cnt, const float* __restrict__ degf,
                          int* __restrict__ localScan, int* __restrict__ blockTotal,
                          float* __restrict__ dinv, float* __restrict__ invdeg) {
    __shared__ int sc[256];
    int b = blockIdx.x, tid = threadIdx.x;
    int node = b * 256 + tid;
    int c = (node < N_NODES) ? cnt[node] : 0;
    sc[tid] = c;
    __syncthreads();
    for (int off = 1; off < 256; off <<= 1) {
        int t = (tid >= off) ? sc[tid - off] : 0;
        __syncthreads();
        sc[tid] += t;
        __syncthreads();
    }
    if (node < N_NODES) {
        localScan[node] = sc[tid] - c;          // exclusive within tile
        float d = degf[node] + 1.0f;            // self-loop
        dinv[node] = rsqrtf(d);
        invdeg[node] = 1.0f / d;
    }
    if (tid == 255) blockTotal[b] = sc[255];
}

// ------- scanB: exclusive scan of tile totals -> tileBase -------------------------
__global__ void scanB(const int* __restrict__ blockTotal, int* __restrict__ tileBase) {
    __shared__ int s[NBUCK];
    for (int i = threadIdx.x; i < NBUCK; i += 256) s[i] = blockTotal[i];
    __syncthreads();
    if (threadIdx.x == 0) {
        int run = 0;
        for (int i = 0; i < NBUCK; ++i) { int t = s[i]; s[i] = run; run += t; }
    }
    __syncthreads();
    for (int i = threadIdx.x; i < NBUCK; i += 256) tileBase[i] = s[i];
}

// ------- rowptr_write: rowptr = tileBase + localScan; cursor copy ------------------
__global__ void rowptr_write(const int* __restrict__ localScan, const int* __restrict__ tileBase,
                             int* __restrict__ rowptr, int* __restrict__ cur) {
    int node = blockIdx.x * 256 + threadIdx.x;
    if (node < N_NODES) {
        int r = tileBase[blockIdx.x] + localScan[node];
        rowptr[node] = r;
        cur[node] = r;
    }
    if (node == 0) rowptr[N_NODES] = N_EDGES;
}

// ------- edge_scatter: one pass, atomic cursor, norm computed inline ---------------
__global__ void edge_scatter(const int* __restrict__ src, const int* __restrict__ dst,
                             const float* __restrict__ w, const float* __restrict__ dinv,
                             int* __restrict__ cur, int2* __restrict__ edata2) {
    int e = blockIdx.x * 256 + threadIdx.x;
    if (e < N_EDGES) {
        int s = src[e], d = dst[e];
        float norm = dinv[s] * w[e] * dinv[d];
        int pos = atomicAdd(&cur[d], 1);
        edata2[pos] = make_int2(s, __float_as_int(norm));
    }
}

// ------- gather-aggregate 64-dim from fp8 rows (writes h2h fp16) -------------------
// Lane layout: s = lane>>4 (edge slot 0..3), q = lane&15 (dims 4q..4q+3).
__global__ void agg64_fused(const int* __restrict__ rowptr, const int2* __restrict__ edata2,
                            const unsigned char* __restrict__ H8, const float* __restrict__ invdeg,
                            const float* __restrict__ b1, _Float16* __restrict__ h2h) {
    const int node = blockIdx.x * 4 + (threadIdx.x >> 6);   // grid exact: 25000*4 = 100k
    const int lane = threadIdx.x & 63;
    const int s = lane >> 4;
    const int q = lane & 15;
    int p = rowptr[node], end = rowptr[node + 1];
    float acc[4][4] = {};
    for (; p + 15 < end; p += 16) {
        int2 e[4];
#pragma unroll
        for (int g = 0; g < 4; ++g) e[g] = edata2[p + 4 * g + s];
        unsigned u[4];
#pragma unroll
        for (int g = 0; g < 4; ++g)
            u[g] = *(const unsigned*)(H8 + ((unsigned)e[g].x << 6) + (q << 2));
#pragma unroll
        for (int g = 0; g < 4; ++g) {
            float n = __int_as_float(e[g].y);
            f32x4 d = dec_fp8x4(u[g]);
#pragma unroll
            for (int j = 0; j < 4; ++j)
                acc[g][j] += n * d[j];
        }
    }
    {
        int r = end - p;
        int2 e[4];
#pragma unroll
        for (int g = 0; g < 4; ++g) {
            e[g] = make_int2(0, 0);
            if (4 * g + s < r) e[g] = edata2[p + 4 * g + s];
        }
        unsigned u[4];
#pragma unroll
        for (int g = 0; g < 4; ++g)
            u[g] = *(const unsigned*)(H8 + ((unsigned)e[g].x << 6) + (q << 2));
#pragma unroll
        for (int g = 0; g < 4; ++g) {
            float n = __int_as_float(e[g].y);
            f32x4 d = dec_fp8x4(u[g]);
#pragma unroll
            for (int j = 0; j < 4; ++j)
                acc[g][j] += n * d[j];
        }
    }
    float v[4];
#pragma unroll
    for (int j = 0; j < 4; ++j) {
        float t = (acc[0][j] + acc[1][j]) + (acc[2][j] + acc[3][j]);
        t += __shfl_xor(t, 16);
        t += __shfl_xor(t, 32);
        v[j] = t;
    }
    unsigned us = *(const unsigned*)(H8 + ((unsigned)node << 6) + (q << 2));
    float idg = invdeg[node];
    f32x4 bv = *(const f32x4*)(b1 + (q << 2));
    if (s == 0) {
        f32x4 ds = dec_fp8x4(us);
        h16x4 hv;
#pragma unroll
        for (int j = 0; j < 4; ++j) {
            float rj = v[j] + ds[j] * idg + bv[j];
            hv[j] = (_Float16)fmaxf(rj, 0.f);
        }
        *(h16x4*)(h2h + ((unsigned)node << 6) + (q << 2)) = hv;
    }
}

// ---------------- hh16 = fp16(h2 @ W2), padded 32-wide rows (accuracy-critical) ----
__global__ void linear30(const _Float16* __restrict__ H, const float* __restrict__ W2,
                         __half* __restrict__ HH16) {
    __shared__ float sW[64 * NC];
    __shared__ float sH[8 * 64];
    for (int i = threadIdx.x; i < 64 * NC; i += blockDim.x) sW[i] = W2[i];
    int node0 = blockIdx.x * 8;
    for (int i = threadIdx.x; i < 8 * 64; i += blockDim.x) {
        int n = node0 + (i >> 6);
        sH[i] = (n < N_NODES) ? (float)H[(size_t)n * 64 + (i & 63)] : 0.f;
    }
    __syncthreads();
    int ln = threadIdx.x >> 5;
    int c = threadIdx.x & 31;
    int node = node0 + ln;
    if (node < N_NODES) {
        float acc = 0.f;
        if (c < NC) {
#pragma unroll
            for (int k = 0; k < 64; ++k) acc += sH[ln * 64 + k] * sW[k * NC + c];
        }
        HH16[(size_t)node * NCP + c] = __float2half(acc);
    }
}

// ------- gather-aggregate 30-dim + softmax: 4 nodes/wave, class-pair lanes ---------
__global__ void agg30_softmax_colsum(const int* __restrict__ rowptr, const int2* __restrict__ edata2,
                                     const __half* __restrict__ HH16,
                                     const float* __restrict__ invdeg,
                                     const float* __restrict__ b2, float* __restrict__ FX,
                                     unsigned char* __restrict__ FX8,
                                     float* __restrict__ colsum_part) {
    const int lane = threadIdx.x & 63;
    const int waveInBlock = threadIdx.x >> 6;
    const int n = lane >> 4;
    const int c2 = lane & 15;
    const bool activeC = (c2 < 15);          // classes 2c2,2c2+1 < 30
    const int node = (blockIdx.x * 4 + waveInBlock) * 4 + n;

    float bb0 = activeC ? b2[2 * c2] : 0.f;
    float bb1 = activeC ? b2[2 * c2 + 1] : 0.f;

    int p = rowptr[node], end = rowptr[node + 1];
    float a0[8], a1[8];
#pragma unroll
    for (int k = 0; k < 8; ++k) { a0[k] = 0.f; a1[k] = 0.f; }
    const __half* __restrict__ Hc = HH16 + (c2 << 1);
    for (; p + 7 < end; p += 8) {
        int2 e[8];
#pragma unroll
        for (int k = 0; k < 8; ++k) e[k] = edata2[p + k];
        unsigned h[8];
#pragma unroll
        for (int k = 0; k < 8; ++k)
            h[k] = *(const unsigned*)(Hc + ((unsigned)e[k].x << 5));
#pragma unroll
        for (int k = 0; k < 8; ++k) {
            float nw = __int_as_float(e[k].y);
            float2 hf = __half22float2(*(const __half2*)&h[k]);
            a0[k] += nw * hf.x;
            a1[k] += nw * hf.y;
        }
    }
    {
        int r = end - p;
        int2 e[8];
#pragma unroll
        for (int k = 0; k < 8; ++k) {
            e[k] = make_int2(0, 0);
            if (k < r) e[k] = edata2[p + k];
        }
        unsigned h[8];
#pragma unroll
        for (int k = 0; k < 8; ++k)
            h[k] = *(const unsigned*)(Hc + ((unsigned)e[k].x << 5));
#pragma unroll
        for (int k = 0; k < 8; ++k) {
            float nw = __int_as_float(e[k].y);
            float2 hf = __half22float2(*(const __half2*)&h[k]);
            a0[k] += nw * hf.x;
            a1[k] += nw * hf.y;
        }
    }
    float s0 = ((a0[0] + a0[1]) + (a0[2] + a0[3])) + ((a0[4] + a0[5]) + (a0[6] + a0[7]));
    float s1 = ((a1[0] + a1[1]) + (a1[2] + a1[3])) + ((a1[4] + a1[5]) + (a1[6] + a1[7]));
    unsigned hsu = *(const unsigned*)(Hc + ((unsigned)node << 5));
    float2 hs = __half22float2(*(const __half2*)&hsu);
    float idg = invdeg[node];
    float x0 = activeC ? (s0 + hs.x * idg + bb0) : -INFINITY;
    float x1 = activeC ? (s1 + hs.y * idg + bb1) : -INFINITY;
    float mx = fmaxf(x0, x1);
    mx = fmaxf(mx, __shfl_xor(mx, 1));
    mx = fmaxf(mx, __shfl_xor(mx, 2));
    mx = fmaxf(mx, __shfl_xor(mx, 4));
    mx = fmaxf(mx, __shfl_xor(mx, 8));
    float e0 = activeC ? expf(x0 - mx) : 0.f;
    float e1 = activeC ? expf(x1 - mx) : 0.f;
    float sum = e0 + e1;
    sum += __shfl_xor(sum, 1);
    sum += __shfl_xor(sum, 2);
    sum += __shfl_xor(sum, 4);
    sum += __shfl_xor(sum, 8);
    float fx0 = e0 / sum;
    float fx1 = e1 / sum;

    if (activeC) {
        *(f32x2*)(FX + (size_t)node * NC + 2 * c2) = (f32x2){fx0, fx1};
        unsigned short pk = (unsigned short)((unsigned)enc_fp8(fx0) | ((unsigned)enc_fp8(fx1) << 8));
        *(unsigned short*)(FX8 + ((unsigned)node << 5) + (c2 << 1)) = pk;
    } else {
        *(unsigned short*)(FX8 + ((unsigned)node << 5) + (c2 << 1)) = 0;   // fp8 +0 pad
    }
    float lacc0 = activeC ? log1pf(-fx0 * fx0) : 0.f;
    float lacc1 = activeC ? log1pf(-fx1 * fx1) : 0.f;
    lacc0 += __shfl_xor(lacc0, 16); lacc0 += __shfl_xor(lacc0, 32);
    lacc1 += __shfl_xor(lacc1, 16); lacc1 += __shfl_xor(lacc1, 32);
    __shared__ float part[4][32];
    if (lane < 16) {
        part[waveInBlock][2 * c2] = lacc0;
        part[waveInBlock][2 * c2 + 1] = lacc1;
    }
    __syncthreads();
    if (threadIdx.x < NC) {
        float v = part[0][threadIdx.x] + part[1][threadIdx.x] +
                  part[2][threadIdx.x] + part[3][threadIdx.x];
        atomicAdd(&colsum_part[(blockIdx.x & 63) * 32 + threadIdx.x], v);
    }
}

// ------- edge loss over ORIGINAL edge order; fp8 FX table (3.2 MB, L2-resident) ----
__global__ void edge_loss_plain(const int* __restrict__ src, const int* __restrict__ dst,
                                const float* __restrict__ w,
                                const unsigned char* __restrict__ FX8,
                                float* __restrict__ mse_part) {
    int e = blockIdx.x * blockDim.x + threadIdx.x;
    float v = 0.f;
    if (e < N_EDGES) {
        int sn = src[e];
        int dn = dst[e];
        const uint4* rs = (const uint4*)(FX8 + (size_t)sn * NCP);
        const uint4* rd = (const uint4*)(FX8 + (size_t)dn * NCP);
        uint4 a0 = rs[0], a1 = rs[1];
        uint4 b0 = rd[0], b1 = rd[1];
        float ff = dot4_fp8(a0.x, b0.x) + dot4_fp8(a0.y, b0.y) +
                   dot4_fp8(a0.z, b0.z) + dot4_fp8(a0.w, b0.w) +
                   dot4_fp8(a1.x, b1.x) + dot4_fp8(a1.y, b1.y) +
                   dot4_fp8(a1.z, b1.z) + dot4_fp8(a1.w, b1.w);
        float diff = ff - w[e];
        v = diff * diff;
    }
    for (int off = 32; off > 0; off >>= 1) v += __shfl_down(v, off);
    __shared__ float ps[4];
    int lane = threadIdx.x & 63, wv = threadIdx.x >> 6;
    if (lane == 0) ps[wv] = v;
    __syncthreads();
    if (threadIdx.x == 0)
        atomicAdd(&mse_part[blockIdx.x & 63], ps[0] + ps[1] + ps[2] + ps[3]);
}

// ---------------- finalize: sum 64-slot partials, preg + loss ----------------
__global__ void finalize(const float* __restrict__ colsum_part, const float* __restrict__ mse_part,
                         float* __restrict__ out_loss) {
    int t = threadIdx.x;          // 64 threads
    float m = mse_part[t];
    for (int off = 32; off > 0; off >>= 1) m += __shfl_down(m, off);
    float term = 0.f;
    if (t < NC) {
        float s = 0.f;
        for (int k = 0; k < 64; ++k) s += colsum_part[k * 32 + t];
        term = logf(1.0001f - expf(s));
    }
    for (int off = 32; off > 0; off >>= 1) term += __shfl_down(term, off);
    if (t == 0)
        out_loss[0] = m / (float)N_EDGES - REG_C * term;
}

extern "C" void kernel_launch(void* const* d_in, const int* in_sizes, int n_in,
                              void* d_out, int out_size, void* d_ws, size_t ws_size,
                              hipStream_t stream) {
    const float* x  = (const float*)d_in[0];
    const int*   ei = (const int*)d_in[1];
    const float* ea = (const float*)d_in[2];
    const float* W1 = (const float*)d_in[3];
    const float* b1 = (const float*)d_in[4];
    const float* W2 = (const float*)d_in[5];
    const float* b2 = (const float*)d_in[6];
    const int* srcI = ei;
    const int* dstI = ei + N_EDGES;

    float* FX   = (float*)d_out;
    float* loss = FX + (size_t)N_NODES * NC;

    // workspace layout -- explicit float-element offsets; int2 offsets even
    float* ws = (float*)d_ws;
    float*         dinv   = ws;                              // N
    float*         invdeg = ws + 100000;                     // N
    unsigned char* h8     = (unsigned char*)(ws + 200000);   // 64N bytes
    _Float16*      h2h    = (_Float16*)(ws + 1800000);       // 64N halves
    __half*        hh16   = (__half*)(ws + 5000000);         // 32N halves
    unsigned char* fx8    = (unsigned char*)(ws + 6600000);  // 32N bytes
    float*         colsum_part = ws + 7400000;               // 2048
    float*         mse_part    = ws + 7402048;               // 64
    int*           rowptr = (int*)(ws + 7402112);            // N+1
    int*           cnt    = (int*)(ws + 7502114);            // N   } contiguous:
    float*         degf   = ws + 7602114;                    // N   } one 800KB memset
    int*           localScan = (int*)(ws + 7702114);         // N
    int*           blockTotal = (int*)(ws + 7802114);        // 391
    int*           tileBase   = (int*)(ws + 7802505);        // 391
    int*           cur    = (int*)(ws + 7802898);            // N
    int2*          edata2 = (int2*)(ws + 7902898);           // E int2 (even ✓)

    hipMemsetAsync(colsum_part, 0, (2048 + 64) * sizeof(float), stream);
    hipMemsetAsync(cnt, 0, 200000 * sizeof(float), stream);   // cnt + degf

    deg_gemm<<<NBLK_A + GEMM_BLOCKS, 256, 0, stream>>>(dstI, ea, cnt, degf, x, W1, h8);
    node_scan<<<NBUCK, 256, 0, stream>>>(cnt, degf, localScan, blockTotal, dinv, invdeg);
    scanB<<<1, 256, 0, stream>>>(blockTotal, tileBase);
    rowptr_write<<<NBUCK, 256, 0, stream>>>(localScan, tileBase, rowptr, cur);
    edge_scatter<<<(N_EDGES + 255) / 256, 256, 0, stream>>>(srcI, dstI, ea, dinv, cur, edata2);
    agg64_fused<<<N_NODES / 4, 256, 0, stream>>>(rowptr, edata2, h8, invdeg, b1, h2h);
    linear30<<<(N_NODES + 7) / 8, 256, 0, stream>>>(h2h, W2, hh16);
    agg30_softmax_colsum<<<N_NODES / 16, 256, 0, stream>>>(rowptr, edata2, hh16, invdeg, b2,
                                                           FX, fx8, colsum_part);
    edge_loss_plain<<<(N_EDGES + 255) / 256, 256, 0, stream>>>(srcI, dstI, ea, fx8, mse_part);
    finalize<<<1, 64, 0, stream>>>(colsum_part, mse_part, loss);
}

// Round 7
// 259.597 us; speedup vs baseline: 1.4025x; 1.4025x over previous
//
#include <hip/hip_runtime.h>
#include <hip/hip_fp16.h>
#include <math.h>

#define N_NODES 100000
#define N_EDGES 1000000
#define IN_DIM 64
#define HID 64
#define NC 30
#define NCP 32              // padded row width for fp16/fp8 feature rows
#define REG_C 0.01f

#define NTILES (N_NODES / 16)     // 6250
#define NBUCK 391                 // coarse bucket = dst >> 8 (256 nodes/bucket)
#define EPB_A 2048                // edges per hist block
#define NBLK_A 489                // ceil(1M / 2048)
#define GEMM_BLOCKS 512

typedef _Float16 half8 __attribute__((ext_vector_type(8)));
typedef _Float16 h16x4 __attribute__((ext_vector_type(4)));
typedef float f32x4 __attribute__((ext_vector_type(4)));
typedef float f32x2 __attribute__((ext_vector_type(2)));

__device__ __forceinline__ unsigned char enc_fp8(float v) {
    return (unsigned char)(__builtin_amdgcn_cvt_pk_fp8_f32(v, v, 0, false) & 0xFF);
}
// decode 4 packed fp8 bytes -> 4 floats (byte-select must be literal constants)
__device__ __forceinline__ f32x4 dec_fp8x4(unsigned u) {
    f32x4 r;
    r[0] = __builtin_amdgcn_cvt_f32_fp8((int)u, 0);
    r[1] = __builtin_amdgcn_cvt_f32_fp8((int)u, 1);
    r[2] = __builtin_amdgcn_cvt_f32_fp8((int)u, 2);
    r[3] = __builtin_amdgcn_cvt_f32_fp8((int)u, 3);
    return r;
}
__device__ __forceinline__ float dot4_fp8(unsigned a, unsigned b) {
    float s = __builtin_amdgcn_cvt_f32_fp8((int)a, 0) * __builtin_amdgcn_cvt_f32_fp8((int)b, 0);
    s += __builtin_amdgcn_cvt_f32_fp8((int)a, 1) * __builtin_amdgcn_cvt_f32_fp8((int)b, 1);
    s += __builtin_amdgcn_cvt_f32_fp8((int)a, 2) * __builtin_amdgcn_cvt_f32_fp8((int)b, 2);
    s += __builtin_amdgcn_cvt_f32_fp8((int)a, 3) * __builtin_amdgcn_cvt_f32_fp8((int)b, 3);
    return s;
}

// ------- fused: per-block LDS bucket histogram (NO global atomics) + h1=fp8(x@W1) --
__global__ void hist_gemm(const int* __restrict__ dst, int* __restrict__ histT,
                          const float* __restrict__ X, const float* __restrict__ W,
                          unsigned char* __restrict__ H8) {
    if (blockIdx.x < NBLK_A) {
        __shared__ int cnt[NBUCK];
        for (int i = threadIdx.x; i < NBUCK; i += 256) cnt[i] = 0;
        __syncthreads();
        int e0 = blockIdx.x * EPB_A;
#pragma unroll
        for (int j = 0; j < 8; ++j) {
            int e = e0 + j * 256 + threadIdx.x;
            if (e < N_EDGES) atomicAdd(&cnt[dst[e] >> 8], 1);
        }
        __syncthreads();
        for (int b = threadIdx.x; b < NBUCK; b += 256)
            histT[b * NBLK_A + blockIdx.x] = cnt[b];
        return;
    }
    // ---- GEMM part ----
    const int lane = threadIdx.x & 63;
    const int wave = threadIdx.x >> 6;
    const int qd = lane >> 4;
    const int l = lane & 15;
    half8 bfrag[2][4];
#pragma unroll
    for (int kb = 0; kb < 2; ++kb)
#pragma unroll
        for (int t = 0; t < 4; ++t)
#pragma unroll
            for (int j = 0; j < 8; ++j)
                bfrag[kb][t][j] = (_Float16)W[(kb * 32 + qd * 8 + j) * 64 + t * 16 + l];

    const int gb = blockIdx.x - NBLK_A;
    const int waveStride = GEMM_BLOCKS * 4;
    for (int ntile = gb * 4 + wave; ntile < NTILES; ntile += waveStride) {
        const int node0 = ntile * 16;
        const float* arow = X + (size_t)(node0 + l) * 64 + qd * 8;
        half8 af0, af1;
#pragma unroll
        for (int j = 0; j < 8; ++j) {
            af0[j] = (_Float16)arow[j];
            af1[j] = (_Float16)arow[32 + j];
        }
        f32x4 acc[4];
#pragma unroll
        for (int t = 0; t < 4; ++t) acc[t] = (f32x4){0.f, 0.f, 0.f, 0.f};
#pragma unroll
        for (int t = 0; t < 4; ++t) {
            acc[t] = __builtin_amdgcn_mfma_f32_16x16x32_f16(af0, bfrag[0][t], acc[t], 0, 0, 0);
            acc[t] = __builtin_amdgcn_mfma_f32_16x16x32_f16(af1, bfrag[1][t], acc[t], 0, 0, 0);
        }
#pragma unroll
        for (int t = 0; t < 4; ++t)
#pragma unroll
            for (int rr = 0; rr < 4; ++rr)
                H8[(size_t)(node0 + qd * 4 + rr) * 64 + t * 16 + l] = enc_fp8(acc[t][rr]);
    }
}

// ------- scanA: per bucket, parallel exclusive scan of per-block counts ------------
// pair-scan: thread t owns elements 2t, 2t+1 (512 slots >= 489)
__global__ void scanA(int* __restrict__ histT, int* __restrict__ bucketTotal) {
    __shared__ int sc[256];
    int b = blockIdx.x, tid = threadIdx.x;
    int i0 = 2 * tid, i1 = 2 * tid + 1;
    int v0 = (i0 < NBLK_A) ? histT[b * NBLK_A + i0] : 0;
    int v1 = (i1 < NBLK_A) ? histT[b * NBLK_A + i1] : 0;
    int ps = v0 + v1;
    sc[tid] = ps;
    __syncthreads();
    for (int off = 1; off < 256; off <<= 1) {
        int t = (tid >= off) ? sc[tid - off] : 0;
        __syncthreads();
        sc[tid] += t;
        __syncthreads();
    }
    int excl = sc[tid] - ps;                 // exclusive over pairs
    if (i0 < NBLK_A) histT[b * NBLK_A + i0] = excl;
    if (i1 < NBLK_A) histT[b * NBLK_A + i1] = excl + v0;
    if (tid == 255) bucketTotal[b] = sc[255];
}

// ------- scatter into coarse bucket regions; bucketBase scan computed in-LDS -------
__global__ void scatter_coarse(const int* __restrict__ src, const int* __restrict__ dst,
                               const float* __restrict__ w, const int* __restrict__ histT,
                               const int* __restrict__ bucketTotal, int* __restrict__ bucketBase,
                               int2* __restrict__ sw, unsigned char* __restrict__ dl) {
    __shared__ int cur[NBUCK];
    __shared__ int sc[256];
    int bl = blockIdx.x, tid = threadIdx.x;
    // pair-scan of bucketTotal (391 <= 512)
    int i0 = 2 * tid, i1 = 2 * tid + 1;
    int v0 = (i0 < NBUCK) ? bucketTotal[i0] : 0;
    int v1 = (i1 < NBUCK) ? bucketTotal[i1] : 0;
    int ps = v0 + v1;
    sc[tid] = ps;
    __syncthreads();
    for (int off = 1; off < 256; off <<= 1) {
        int t = (tid >= off) ? sc[tid - off] : 0;
        __syncthreads();
        sc[tid] += t;
        __syncthreads();
    }
    int excl = sc[tid] - ps;
    if (i0 < NBUCK) cur[i0] = excl + histT[i0 * NBLK_A + bl];
    if (i1 < NBUCK) cur[i1] = excl + v0 + histT[i1 * NBLK_A + bl];
    if (bl == 0) {                       // publish bucketBase for fused_bucket
        if (i0 < NBUCK) bucketBase[i0] = excl;
        if (i1 < NBUCK) bucketBase[i1] = excl + v0;
        if (tid == 0) bucketBase[NBUCK] = N_EDGES;
    }
    __syncthreads();
    int e0 = bl * EPB_A;
#pragma unroll
    for (int j = 0; j < 8; ++j) {
        int e = e0 + j * 256 + threadIdx.x;
        if (e < N_EDGES) {
            int d = dst[e];
            int pos = atomicAdd(&cur[d >> 8], 1);
            sw[pos] = make_int2(src[e], __float_as_int(w[e]));
            dl[pos] = (unsigned char)(d & 255);
        }
    }
}

// ------- fused bucket: deg + dinv/invdeg/rowptr + scatter (one kernel) -------------
// edata2.y = w * dinv[dst]  (dinv[src] deferred to the gather kernels)
__global__ void fused_bucket(const int2* __restrict__ sw, const unsigned char* __restrict__ dl,
                             const int* __restrict__ bucketBase, float* __restrict__ dinv,
                             float* __restrict__ invdeg, int* __restrict__ rowptr,
                             int2* __restrict__ edata2) {
    __shared__ int cnt[256];
    __shared__ float degf[256];
    __shared__ int sc[256];
    __shared__ float ldinv[256];
    __shared__ int cur[256];
    int b = blockIdx.x, tid = threadIdx.x;
    cnt[tid] = 0; degf[tid] = 0.f;
    __syncthreads();
    int p0 = bucketBase[b], p1 = bucketBase[b + 1];
    for (int p = p0 + tid; p < p1; p += 256) {
        int d = dl[p];
        atomicAdd(&cnt[d], 1);
        atomicAdd(&degf[d], __int_as_float(sw[p].y));
    }
    __syncthreads();
    int c = cnt[tid];
    sc[tid] = c;
    __syncthreads();
    for (int off = 1; off < 256; off <<= 1) {
        int t = (tid >= off) ? sc[tid - off] : 0;
        __syncthreads();
        sc[tid] += t;
        __syncthreads();
    }
    int node = b * 256 + tid;
    int row = p0 + sc[tid] - c;              // exclusive
    float dv = 0.f;
    if (node < N_NODES) {
        float d = degf[tid] + 1.0f;          // self-loop
        dv = rsqrtf(d);
        dinv[node] = dv;
        invdeg[node] = 1.0f / d;
        rowptr[node] = row;
    }
    ldinv[tid] = dv;
    cur[tid] = row;
    __syncthreads();
    for (int p = p0 + tid; p < p1; p += 256) {
        int d = dl[p];
        int2 r = sw[p];
        float nw = __int_as_float(r.y) * ldinv[d];
        int pos = atomicAdd(&cur[d], 1);
        edata2[pos] = make_int2(r.x, __float_as_int(nw));
    }
    if (b == 0 && tid == 0) rowptr[N_NODES] = N_EDGES;
}

// ------- gather-aggregate 64-dim from fp8 rows (norm completed with dinv[src]) -----
// Lane layout: s = lane>>4 (edge slot 0..3), q = lane&15 (dims 4q..4q+3).
__global__ void agg64_fused(const int* __restrict__ rowptr, const int2* __restrict__ edata2,
                            const unsigned char* __restrict__ H8, const float* __restrict__ dinv,
                            const float* __restrict__ invdeg,
                            const float* __restrict__ b1, _Float16* __restrict__ h2h) {
    const int node = blockIdx.x * 4 + (threadIdx.x >> 6);   // grid exact: 25000*4 = 100k
    const int lane = threadIdx.x & 63;
    const int s = lane >> 4;
    const int q = lane & 15;
    int p = rowptr[node], end = rowptr[node + 1];
    float acc[4][4] = {};
    for (; p + 15 < end; p += 16) {
        int2 e[4];
#pragma unroll
        for (int g = 0; g < 4; ++g) e[g] = edata2[p + 4 * g + s];
        unsigned u[4];
        float dv[4];
#pragma unroll
        for (int g = 0; g < 4; ++g) {
            u[g] = *(const unsigned*)(H8 + ((unsigned)e[g].x << 6) + (q << 2));
            dv[g] = dinv[e[g].x];
        }
#pragma unroll
        for (int g = 0; g < 4; ++g) {
            float n = dv[g] * __int_as_float(e[g].y);
            f32x4 d = dec_fp8x4(u[g]);
#pragma unroll
            for (int j = 0; j < 4; ++j)
                acc[g][j] += n * d[j];
        }
    }
    {
        int r = end - p;
        int2 e[4];
#pragma unroll
        for (int g = 0; g < 4; ++g) {
            e[g] = make_int2(0, 0);
            if (4 * g + s < r) e[g] = edata2[p + 4 * g + s];
        }
        unsigned u[4];
        float dv[4];
#pragma unroll
        for (int g = 0; g < 4; ++g) {
            u[g] = *(const unsigned*)(H8 + ((unsigned)e[g].x << 6) + (q << 2));
            dv[g] = dinv[e[g].x];
        }
#pragma unroll
        for (int g = 0; g < 4; ++g) {
            float n = dv[g] * __int_as_float(e[g].y);
            f32x4 d = dec_fp8x4(u[g]);
#pragma unroll
            for (int j = 0; j < 4; ++j)
                acc[g][j] += n * d[j];
        }
    }
    float v[4];
#pragma unroll
    for (int j = 0; j < 4; ++j) {
        float t = (acc[0][j] + acc[1][j]) + (acc[2][j] + acc[3][j]);
        t += __shfl_xor(t, 16);
        t += __shfl_xor(t, 32);
        v[j] = t;
    }
    unsigned us = *(const unsigned*)(H8 + ((unsigned)node << 6) + (q << 2));
    float idg = invdeg[node];
    f32x4 bv = *(const f32x4*)(b1 + (q << 2));
    if (s == 0) {
        f32x4 ds = dec_fp8x4(us);
        h16x4 hv;
#pragma unroll
        for (int j = 0; j < 4; ++j) {
            float rj = v[j] + ds[j] * idg + bv[j];
            hv[j] = (_Float16)fmaxf(rj, 0.f);
        }
        *(h16x4*)(h2h + ((unsigned)node << 6) + (q << 2)) = hv;
    }
}

// ---------------- hh16 = fp16(h2 @ W2), padded 32-wide rows (accuracy-critical) ----
__global__ void linear30(const _Float16* __restrict__ H, const float* __restrict__ W2,
                         __half* __restrict__ HH16) {
    __shared__ float sW[64 * NC];
    __shared__ float sH[8 * 64];
    for (int i = threadIdx.x; i < 64 * NC; i += blockDim.x) sW[i] = W2[i];
    int node0 = blockIdx.x * 8;
    for (int i = threadIdx.x; i < 8 * 64; i += blockDim.x) {
        int n = node0 + (i >> 6);
        sH[i] = (n < N_NODES) ? (float)H[(size_t)n * 64 + (i & 63)] : 0.f;
    }
    __syncthreads();
    int ln = threadIdx.x >> 5;
    int c = threadIdx.x & 31;
    int node = node0 + ln;
    if (node < N_NODES) {
        float acc = 0.f;
        if (c < NC) {
#pragma unroll
            for (int k = 0; k < 64; ++k) acc += sH[ln * 64 + k] * sW[k * NC + c];
        }
        HH16[(size_t)node * NCP + c] = __float2half(acc);
    }
}

// ------- gather-aggregate 30-dim + softmax: 4 nodes/wave, class-pair lanes ---------
__global__ void agg30_softmax_colsum(const int* __restrict__ rowptr, const int2* __restrict__ edata2,
                                     const __half* __restrict__ HH16, const float* __restrict__ dinv,
                                     const float* __restrict__ invdeg,
                                     const float* __restrict__ b2, float* __restrict__ FX,
                                     unsigned char* __restrict__ FX8,
                                     float* __restrict__ colsum_part) {
    const int lane = threadIdx.x & 63;
    const int waveInBlock = threadIdx.x >> 6;
    const int n = lane >> 4;
    const int c2 = lane & 15;
    const bool activeC = (c2 < 15);          // classes 2c2,2c2+1 < 30
    const int node = (blockIdx.x * 4 + waveInBlock) * 4 + n;

    float bb0 = activeC ? b2[2 * c2] : 0.f;
    float bb1 = activeC ? b2[2 * c2 + 1] : 0.f;

    int p = rowptr[node], end = rowptr[node + 1];
    float a0[8], a1[8];
#pragma unroll
    for (int k = 0; k < 8; ++k) { a0[k] = 0.f; a1[k] = 0.f; }
    const __half* __restrict__ Hc = HH16 + (c2 << 1);
    for (; p + 7 < end; p += 8) {
        int2 e[8];
#pragma unroll
        for (int k = 0; k < 8; ++k) e[k] = edata2[p + k];
        unsigned h[8];
        float dv[8];
#pragma unroll
        for (int k = 0; k < 8; ++k) {
            h[k] = *(const unsigned*)(Hc + ((unsigned)e[k].x << 5));
            dv[k] = dinv[e[k].x];
        }
#pragma unroll
        for (int k = 0; k < 8; ++k) {
            float nw = dv[k] * __int_as_float(e[k].y);
            float2 hf = __half22float2(*(const __half2*)&h[k]);
            a0[k] += nw * hf.x;
            a1[k] += nw * hf.y;
        }
    }
    {
        int r = end - p;
        int2 e[8];
#pragma unroll
        for (int k = 0; k < 8; ++k) {
            e[k] = make_int2(0, 0);
            if (k < r) e[k] = edata2[p + k];
        }
        unsigned h[8];
        float dv[8];
#pragma unroll
        for (int k = 0; k < 8; ++k) {
            h[k] = *(const unsigned*)(Hc + ((unsigned)e[k].x << 5));
            dv[k] = dinv[e[k].x];
        }
#pragma unroll
        for (int k = 0; k < 8; ++k) {
            float nw = dv[k] * __int_as_float(e[k].y);
            float2 hf = __half22float2(*(const __half2*)&h[k]);
            a0[k] += nw * hf.x;
            a1[k] += nw * hf.y;
        }
    }
    float s0 = ((a0[0] + a0[1]) + (a0[2] + a0[3])) + ((a0[4] + a0[5]) + (a0[6] + a0[7]));
    float s1 = ((a1[0] + a1[1]) + (a1[2] + a1[3])) + ((a1[4] + a1[5]) + (a1[6] + a1[7]));
    unsigned hsu = *(const unsigned*)(Hc + ((unsigned)node << 5));
    float2 hs = __half22float2(*(const __half2*)&hsu);
    float idg = invdeg[node];
    float x0 = activeC ? (s0 + hs.x * idg + bb0) : -INFINITY;
    float x1 = activeC ? (s1 + hs.y * idg + bb1) : -INFINITY;
    float mx = fmaxf(x0, x1);
    mx = fmaxf(mx, __shfl_xor(mx, 1));
    mx = fmaxf(mx, __shfl_xor(mx, 2));
    mx = fmaxf(mx, __shfl_xor(mx, 4));
    mx = fmaxf(mx, __shfl_xor(mx, 8));
    float e0 = activeC ? expf(x0 - mx) : 0.f;
    float e1 = activeC ? expf(x1 - mx) : 0.f;
    float sum = e0 + e1;
    sum += __shfl_xor(sum, 1);
    sum += __shfl_xor(sum, 2);
    sum += __shfl_xor(sum, 4);
    sum += __shfl_xor(sum, 8);
    float fx0 = e0 / sum;
    float fx1 = e1 / sum;

    if (activeC) {
        *(f32x2*)(FX + (size_t)node * NC + 2 * c2) = (f32x2){fx0, fx1};
        unsigned short pk = (unsigned short)((unsigned)enc_fp8(fx0) | ((unsigned)enc_fp8(fx1) << 8));
        *(unsigned short*)(FX8 + ((unsigned)node << 5) + (c2 << 1)) = pk;
    } else {
        *(unsigned short*)(FX8 + ((unsigned)node << 5) + (c2 << 1)) = 0;   // fp8 +0 pad
    }
    float lacc0 = activeC ? log1pf(-fx0 * fx0) : 0.f;
    float lacc1 = activeC ? log1pf(-fx1 * fx1) : 0.f;
    lacc0 += __shfl_xor(lacc0, 16); lacc0 += __shfl_xor(lacc0, 32);
    lacc1 += __shfl_xor(lacc1, 16); lacc1 += __shfl_xor(lacc1, 32);
    __shared__ float part[4][32];
    if (lane < 16) {
        part[waveInBlock][2 * c2] = lacc0;
        part[waveInBlock][2 * c2 + 1] = lacc1;
    }
    __syncthreads();
    if (threadIdx.x < NC) {
        float v = part[0][threadIdx.x] + part[1][threadIdx.x] +
                  part[2][threadIdx.x] + part[3][threadIdx.x];
        atomicAdd(&colsum_part[(blockIdx.x & 63) * 32 + threadIdx.x], v);
    }
}

// ------- edge loss over ORIGINAL edge order; fp8 FX table (3.2 MB, L2-resident) ----
__global__ void edge_loss_plain(const int* __restrict__ src, const int* __restrict__ dst,
                                const float* __restrict__ w,
                                const unsigned char* __restrict__ FX8,
                                float* __restrict__ mse_part) {
    int e = blockIdx.x * blockDim.x + threadIdx.x;
    float v = 0.f;
    if (e < N_EDGES) {
        int sn = src[e];
        int dn = dst[e];
        const uint4* rs = (const uint4*)(FX8 + (size_t)sn * NCP);
        const uint4* rd = (const uint4*)(FX8 + (size_t)dn * NCP);
        uint4 a0 = rs[0], a1 = rs[1];
        uint4 b0 = rd[0], b1 = rd[1];
        float ff = dot4_fp8(a0.x, b0.x) + dot4_fp8(a0.y, b0.y) +
                   dot4_fp8(a0.z, b0.z) + dot4_fp8(a0.w, b0.w) +
                   dot4_fp8(a1.x, b1.x) + dot4_fp8(a1.y, b1.y) +
                   dot4_fp8(a1.z, b1.z) + dot4_fp8(a1.w, b1.w);
        float diff = ff - w[e];
        v = diff * diff;
    }
    for (int off = 32; off > 0; off >>= 1) v += __shfl_down(v, off);
    __shared__ float ps[4];
    int lane = threadIdx.x & 63, wv = threadIdx.x >> 6;
    if (lane == 0) ps[wv] = v;
    __syncthreads();
    if (threadIdx.x == 0)
        atomicAdd(&mse_part[blockIdx.x & 63], ps[0] + ps[1] + ps[2] + ps[3]);
}

// ---------------- finalize: sum 64-slot partials, preg + loss ----------------
__global__ void finalize(const float* __restrict__ colsum_part, const float* __restrict__ mse_part,
                         float* __restrict__ out_loss) {
    int t = threadIdx.x;          // 64 threads
    float m = mse_part[t];
    for (int off = 32; off > 0; off >>= 1) m += __shfl_down(m, off);
    float term = 0.f;
    if (t < NC) {
        float s = 0.f;
        for (int k = 0; k < 64; ++k) s += colsum_part[k * 32 + t];
        term = logf(1.0001f - expf(s));
    }
    for (int off = 32; off > 0; off >>= 1) term += __shfl_down(term, off);
    if (t == 0)
        out_loss[0] = m / (float)N_EDGES - REG_C * term;
}

extern "C" void kernel_launch(void* const* d_in, const int* in_sizes, int n_in,
                              void* d_out, int out_size, void* d_ws, size_t ws_size,
                              hipStream_t stream) {
    const float* x  = (const float*)d_in[0];
    const int*   ei = (const int*)d_in[1];
    const float* ea = (const float*)d_in[2];
    const float* W1 = (const float*)d_in[3];
    const float* b1 = (const float*)d_in[4];
    const float* W2 = (const float*)d_in[5];
    const float* b2 = (const float*)d_in[6];
    const int* srcI = ei;
    const int* dstI = ei + N_EDGES;

    float* FX   = (float*)d_out;
    float* loss = FX + (size_t)N_NODES * NC;

    // workspace layout -- explicit float-element offsets; int2 offsets even
    float* ws = (float*)d_ws;
    float*         dinv   = ws;                              // N
    float*         invdeg = ws + 100000;                     // N
    unsigned char* h8     = (unsigned char*)(ws + 200000);   // 64N bytes
    _Float16*      h2h    = (_Float16*)(ws + 1800000);       // 64N halves
    __half*        hh16   = (__half*)(ws + 5000000);         // 32N halves
    unsigned char* fx8    = (unsigned char*)(ws + 6600000);  // 32N bytes
    float*         colsum_part = ws + 7400000;               // 2048
    float*         mse_part    = ws + 7402048;               // 64
    int*           rowptr = (int*)(ws + 7402112);            // N+1
    int*           histT  = (int*)(ws + 7502114);            // NBUCK*NBLK_A = 191199
    int*           bucketTotal = (int*)(ws + 7693314);       // 391
    int*           bucketBase  = (int*)(ws + 7693706);       // 392
    int2*          sw     = (int2*)(ws + 7694098);           // E int2 (even ✓)
    unsigned char* dl     = (unsigned char*)(ws + 9694098);  // E bytes
    int2*          edata2 = (int2*)(ws + 9944098);           // E int2 (even ✓)

    hipMemsetAsync(colsum_part, 0, (2048 + 64) * sizeof(float), stream);

    hist_gemm<<<NBLK_A + GEMM_BLOCKS, 256, 0, stream>>>(dstI, histT, x, W1, h8);
    scanA<<<NBUCK, 256, 0, stream>>>(histT, bucketTotal);
    scatter_coarse<<<NBLK_A, 256, 0, stream>>>(srcI, dstI, ea, histT, bucketTotal,
                                               bucketBase, sw, dl);
    fused_bucket<<<NBUCK, 256, 0, stream>>>(sw, dl, bucketBase, dinv, invdeg, rowptr, edata2);
    agg64_fused<<<N_NODES / 4, 256, 0, stream>>>(rowptr, edata2, h8, dinv, invdeg, b1, h2h);
    linear30<<<(N_NODES + 7) / 8, 256, 0, stream>>>(h2h, W2, hh16);
    agg30_softmax_colsum<<<N_NODES / 16, 256, 0, stream>>>(rowptr, edata2, hh16, dinv, invdeg,
                                                           b2, FX, fx8, colsum_part);
    edge_loss_plain<<<(N_EDGES + 255) / 256, 256, 0, stream>>>(srcI, dstI, ea, fx8, mse_part);
    finalize<<<1, 64, 0, stream>>>(colsum_part, mse_part, loss);
}